// Round 1
// baseline (1959.039 us; speedup 1.0000x reference)
//
#include <hip/hip_runtime.h>
#include <math.h>

#define D_MODEL 512
#define NHEADS 8
#define DK 64
#define BATCH 2
#define SEQ 4096
#define SCALE 8.0f   // sqrt(64)

// ============================================================================
// GEMM: C[M,N] = alpha * (A[M,K] @ W[N,K]^T + bias[N])   (torch Linear layout)
// fp32, LDS-tiled 64x64x16, 4x4 register micro-tile per thread, 256 threads.
// ============================================================================
#define GBM 64
#define GBN 64
#define GBK 16

__global__ __launch_bounds__(256)
void gemm_nt_bias(const float* __restrict__ A, const float* __restrict__ W,
                  const float* __restrict__ bias, float* __restrict__ C,
                  int M, int N, int K, float alpha) {
    // k-major tiles; +1 pad breaks stride-64 bank aliasing on the transpose store
    __shared__ float As[GBK][GBM + 1];
    __shared__ float Ws[GBK][GBN + 1];

    const int t  = threadIdx.x;
    const int tx = t & 15;    // -> n (4 cols)
    const int ty = t >> 4;    // -> m (4 rows)
    const int m0 = blockIdx.y * GBM;
    const int n0 = blockIdx.x * GBN;

    const int lrow = t >> 2;  // 0..63 tile row
    const int lseg = t & 3;   // float4 segment along k (16 = 4 segs)

    float acc[4][4] = {};

    for (int k0 = 0; k0 < K; k0 += GBK) {
        // issue global loads before the barrier so they overlap prior compute
        float4 av = *(const float4*)(A + (size_t)(m0 + lrow) * K + k0 + lseg * 4);
        float4 wv = *(const float4*)(W + (size_t)(n0 + lrow) * K + k0 + lseg * 4);
        __syncthreads();   // previous iteration's LDS reads complete
        As[lseg * 4 + 0][lrow] = av.x;
        As[lseg * 4 + 1][lrow] = av.y;
        As[lseg * 4 + 2][lrow] = av.z;
        As[lseg * 4 + 3][lrow] = av.w;
        Ws[lseg * 4 + 0][lrow] = wv.x;
        Ws[lseg * 4 + 1][lrow] = wv.y;
        Ws[lseg * 4 + 2][lrow] = wv.z;
        Ws[lseg * 4 + 3][lrow] = wv.w;
        __syncthreads();

        #pragma unroll
        for (int k = 0; k < GBK; ++k) {
            float a[4], w[4];
            #pragma unroll
            for (int i = 0; i < 4; ++i) a[i] = As[k][ty * 4 + i];
            #pragma unroll
            for (int j = 0; j < 4; ++j) w[j] = Ws[k][tx * 4 + j];
            #pragma unroll
            for (int i = 0; i < 4; ++i)
                #pragma unroll
                for (int j = 0; j < 4; ++j)
                    acc[i][j] = fmaf(a[i], w[j], acc[i][j]);
        }
    }

    #pragma unroll
    for (int i = 0; i < 4; ++i) {
        float4 o;
        o.x = alpha * (acc[i][0] + bias[n0 + tx * 4 + 0]);
        o.y = alpha * (acc[i][1] + bias[n0 + tx * 4 + 1]);
        o.z = alpha * (acc[i][2] + bias[n0 + tx * 4 + 2]);
        o.w = alpha * (acc[i][3] + bias[n0 + tx * 4 + 3]);
        *(float4*)(C + (size_t)(m0 + ty * 4 + i) * N + n0 + tx * 4) = o;
    }
}

// ============================================================================
// Flash-style attention, fp32. Q pre-scaled by 1/SCALE.
// Block = 256 threads handles one (b, h, 64-query tile). Iterates 64-key tiles.
// Online softmax: running m,l per row in LDS; O in registers (4x4 per thread).
// Layout: Q/K/V/O are [B, S, D_MODEL] with head h at column offset h*DK.
// ============================================================================
#define AQ 64
#define AK 64

__global__ __launch_bounds__(256)
void attn_kernel(const float* __restrict__ Q, const float* __restrict__ Kg,
                 const float* __restrict__ V, float* __restrict__ O) {
    __shared__ float Qs[AQ][DK + 1];
    __shared__ float Ks[AK][DK + 1];
    __shared__ float Vs[AK][DK + 1];
    __shared__ float Ps[AQ][AK + 1];
    __shared__ float m_s[AQ];
    __shared__ float l_s[AQ];

    const int t  = threadIdx.x;
    const int tx = t & 15;   // -> 4 key cols / 4 dims
    const int ty = t >> 4;   // -> 4 query rows
    const int q0 = blockIdx.x * AQ;
    const int h  = blockIdx.y;
    const int b  = blockIdx.z;

    const size_t base = (size_t)b * SEQ * D_MODEL + (size_t)h * DK;

    // ---- load Q tile (64 rows x 64 floats) ----
    {
        const int lrow = t >> 2, lseg = t & 3;
        const float* src = Q + base + (size_t)(q0 + lrow) * D_MODEL + lseg * 16;
        #pragma unroll
        for (int u = 0; u < 4; ++u) {
            float4 v = *(const float4*)(src + u * 4);
            Qs[lrow][lseg * 16 + u * 4 + 0] = v.x;
            Qs[lrow][lseg * 16 + u * 4 + 1] = v.y;
            Qs[lrow][lseg * 16 + u * 4 + 2] = v.z;
            Qs[lrow][lseg * 16 + u * 4 + 3] = v.w;
        }
    }
    if (t < AQ) { m_s[t] = -INFINITY; l_s[t] = 0.0f; }

    float o[4][4] = {};

    for (int k0 = 0; k0 < SEQ; k0 += AK) {
        __syncthreads();   // prior iteration done with Ks/Vs/Ps (covers init on iter 0)
        // ---- load K,V tiles ----
        {
            const int lrow = t >> 2, lseg = t & 3;
            const float* ks = Kg + base + (size_t)(k0 + lrow) * D_MODEL + lseg * 16;
            const float* vs = V  + base + (size_t)(k0 + lrow) * D_MODEL + lseg * 16;
            #pragma unroll
            for (int u = 0; u < 4; ++u) {
                float4 kv = *(const float4*)(ks + u * 4);
                float4 vv = *(const float4*)(vs + u * 4);
                Ks[lrow][lseg * 16 + u * 4 + 0] = kv.x;
                Ks[lrow][lseg * 16 + u * 4 + 1] = kv.y;
                Ks[lrow][lseg * 16 + u * 4 + 2] = kv.z;
                Ks[lrow][lseg * 16 + u * 4 + 3] = kv.w;
                Vs[lrow][lseg * 16 + u * 4 + 0] = vv.x;
                Vs[lrow][lseg * 16 + u * 4 + 1] = vv.y;
                Vs[lrow][lseg * 16 + u * 4 + 2] = vv.z;
                Vs[lrow][lseg * 16 + u * 4 + 3] = vv.w;
            }
        }
        __syncthreads();

        // ---- S tile = Qs @ Ks^T (Q already carries 1/SCALE) ----
        float s[4][4] = {};
        #pragma unroll 8
        for (int d = 0; d < DK; ++d) {
            float a[4], kk[4];
            #pragma unroll
            for (int i = 0; i < 4; ++i) a[i]  = Qs[ty * 4 + i][d];
            #pragma unroll
            for (int j = 0; j < 4; ++j) kk[j] = Ks[tx * 4 + j][d];
            #pragma unroll
            for (int i = 0; i < 4; ++i)
                #pragma unroll
                for (int j = 0; j < 4; ++j)
                    s[i][j] = fmaf(a[i], kk[j], s[i][j]);
        }

        // ---- online softmax per query row ----
        #pragma unroll
        for (int i = 0; i < 4; ++i) {
            const int q = ty * 4 + i;
            float mloc = fmaxf(fmaxf(s[i][0], s[i][1]), fmaxf(s[i][2], s[i][3]));
            #pragma unroll
            for (int off = 1; off < 16; off <<= 1)
                mloc = fmaxf(mloc, __shfl_xor(mloc, off));
            const float mold = m_s[q];              // wave-coherent: owner group only
            const float mnew = fmaxf(mold, mloc);
            const float al   = __expf(mold - mnew); // exp(-inf)=0 on iter 0
            float rsum = 0.0f;
            #pragma unroll
            for (int j = 0; j < 4; ++j) {
                const float p = __expf(s[i][j] - mnew);
                Ps[q][tx * 4 + j] = p;
                rsum += p;
            }
            #pragma unroll
            for (int off = 1; off < 16; off <<= 1)
                rsum += __shfl_xor(rsum, off);
            #pragma unroll
            for (int j = 0; j < 4; ++j) o[i][j] *= al;
            if (tx == 0) { m_s[q] = mnew; l_s[q] = l_s[q] * al + rsum; }
        }
        __syncthreads();   // Ps visible to all waves

        // ---- O += Ps @ Vs ----
        #pragma unroll 8
        for (int k = 0; k < AK; ++k) {
            float p[4], v[4];
            #pragma unroll
            for (int i = 0; i < 4; ++i) p[i] = Ps[ty * 4 + i][k];
            #pragma unroll
            for (int j = 0; j < 4; ++j) v[j] = Vs[k][tx * 4 + j];
            #pragma unroll
            for (int i = 0; i < 4; ++i)
                #pragma unroll
                for (int j = 0; j < 4; ++j)
                    o[i][j] = fmaf(p[i], v[j], o[i][j]);
        }
    }

    // ---- normalize and store ----
    #pragma unroll
    for (int i = 0; i < 4; ++i) {
        const float inv = 1.0f / l_s[ty * 4 + i];   // written by same wave's tx==0
        float4 ov = { o[i][0] * inv, o[i][1] * inv, o[i][2] * inv, o[i][3] * inv };
        *(float4*)(O + base + (size_t)(q0 + ty * 4 + i) * D_MODEL + tx * 4) = ov;
    }
}

// ============================================================================
extern "C" void kernel_launch(void* const* d_in, const int* in_sizes, int n_in,
                              void* d_out, int out_size, void* d_ws, size_t ws_size,
                              hipStream_t stream) {
    const float* query = (const float*)d_in[0];
    const float* key   = (const float*)d_in[1];
    const float* value = (const float*)d_in[2];
    const float* w_q   = (const float*)d_in[3];
    const float* b_q   = (const float*)d_in[4];
    const float* w_k   = (const float*)d_in[5];
    const float* b_k   = (const float*)d_in[6];
    const float* w_v   = (const float*)d_in[7];
    const float* b_v   = (const float*)d_in[8];
    const float* w_o   = (const float*)d_in[9];
    const float* b_o   = (const float*)d_in[10];
    float* out = (float*)d_out;

    const int M = BATCH * SEQ;               // 8192 rows
    const size_t plane = (size_t)M * D_MODEL; // 4 Mi floats = 16 MB

    float* Qb = (float*)d_ws;
    float* Kb = Qb + plane;
    float* Vb = Kb + plane;
    float* Ab = Vb + plane;                  // total ws use: 64 MB

    dim3 blk(256);
    dim3 ggrid(D_MODEL / GBN, M / GBM);      // (8, 128)

    // projections; fold 1/SCALE into Q (scales bias too, matching (xW^T+b)/SCALE)
    hipLaunchKernelGGL(gemm_nt_bias, ggrid, blk, 0, stream,
                       query, w_q, b_q, Qb, M, D_MODEL, D_MODEL, 1.0f / SCALE);
    hipLaunchKernelGGL(gemm_nt_bias, ggrid, blk, 0, stream,
                       key,   w_k, b_k, Kb, M, D_MODEL, D_MODEL, 1.0f);
    hipLaunchKernelGGL(gemm_nt_bias, ggrid, blk, 0, stream,
                       value, w_v, b_v, Vb, M, D_MODEL, D_MODEL, 1.0f);

    dim3 agrid(SEQ / AQ, NHEADS, BATCH);     // (64, 8, 2)
    hipLaunchKernelGGL(attn_kernel, agrid, blk, 0, stream, Qb, Kb, Vb, Ab);

    // output projection
    hipLaunchKernelGGL(gemm_nt_bias, ggrid, blk, 0, stream,
                       Ab, w_o, b_o, out, M, D_MODEL, D_MODEL, 1.0f);
}

// Round 3
// 673.977 us; speedup vs baseline: 2.9067x; 2.9067x over previous
//
#include <hip/hip_runtime.h>
#include <math.h>

#define D_MODEL 512
#define NHEADS 8
#define DK 64
#define BATCH 2
#define SEQ 4096
// log2(e)/8 folded into the Q projection: scores come out in log2 domain,
// softmax uses exp2 directly (v_exp_f32 is natively 2^x).
#define ATTN_SCALE 0.18033688011112043f

typedef _Float16 half8 __attribute__((ext_vector_type(8)));
typedef __fp16 pkhalf2 __attribute__((ext_vector_type(2)));   // cvt_pkrtz result type
typedef float f32x4 __attribute__((ext_vector_type(4)));

__device__ __forceinline__ void pack4_store(_Float16* dst, float4 v) {
    union { pkhalf2 h[2]; uint2 u; } z;
    z.h[0] = __builtin_amdgcn_cvt_pkrtz(v.x, v.y);
    z.h[1] = __builtin_amdgcn_cvt_pkrtz(v.z, v.w);
    *(uint2*)dst = z.u;   // 8B-aligned by construction (row stride 144B, col*2 multiple of 8)
}

// ============================================================================
// GEMM: C = alpha * (A[M,K] @ W[N,K]^T + bias)   fp32, 64x64x16 tiles.
// transpose_out=1 writes C^T into per-head [b][h][d][s] layout (for V).
// ============================================================================
#define GBM 64
#define GBN 64
#define GBK 16

__global__ __launch_bounds__(256)
void gemm_nt_bias(const float* __restrict__ A, const float* __restrict__ W,
                  const float* __restrict__ bias, float* __restrict__ C,
                  int M, int N, int K, float alpha, int transpose_out) {
    __shared__ float As[GBK][GBM + 1];
    __shared__ float Ws[GBK][GBN + 1];

    const int t  = threadIdx.x;
    const int tx = t & 15;
    const int ty = t >> 4;
    const int m0 = blockIdx.y * GBM;
    const int n0 = blockIdx.x * GBN;

    const int lrow = t >> 2;
    const int lseg = t & 3;

    float acc[4][4] = {};

    for (int k0 = 0; k0 < K; k0 += GBK) {
        float4 av = *(const float4*)(A + (size_t)(m0 + lrow) * K + k0 + lseg * 4);
        float4 wv = *(const float4*)(W + (size_t)(n0 + lrow) * K + k0 + lseg * 4);
        __syncthreads();
        As[lseg * 4 + 0][lrow] = av.x;
        As[lseg * 4 + 1][lrow] = av.y;
        As[lseg * 4 + 2][lrow] = av.z;
        As[lseg * 4 + 3][lrow] = av.w;
        Ws[lseg * 4 + 0][lrow] = wv.x;
        Ws[lseg * 4 + 1][lrow] = wv.y;
        Ws[lseg * 4 + 2][lrow] = wv.z;
        Ws[lseg * 4 + 3][lrow] = wv.w;
        __syncthreads();

        #pragma unroll
        for (int k = 0; k < GBK; ++k) {
            float a[4], w[4];
            #pragma unroll
            for (int i = 0; i < 4; ++i) a[i] = As[k][ty * 4 + i];
            #pragma unroll
            for (int j = 0; j < 4; ++j) w[j] = Ws[k][tx * 4 + j];
            #pragma unroll
            for (int i = 0; i < 4; ++i)
                #pragma unroll
                for (int j = 0; j < 4; ++j)
                    acc[i][j] = fmaf(a[i], w[j], acc[i][j]);
        }
    }

    if (!transpose_out) {
        #pragma unroll
        for (int i = 0; i < 4; ++i) {
            float4 o;
            o.x = alpha * (acc[i][0] + bias[n0 + tx * 4 + 0]);
            o.y = alpha * (acc[i][1] + bias[n0 + tx * 4 + 1]);
            o.z = alpha * (acc[i][2] + bias[n0 + tx * 4 + 2]);
            o.w = alpha * (acc[i][3] + bias[n0 + tx * 4 + 3]);
            *(float4*)(C + (size_t)(m0 + ty * 4 + i) * N + n0 + tx * 4) = o;
        }
    } else {
        // C^T into [b][h][d][s]; float4 runs along s (= m). alpha assumed 1.
        #pragma unroll
        for (int j = 0; j < 4; ++j) {
            const int n = n0 + tx * 4 + j;
            const float bv = bias[n];
            float4 o = { acc[0][j] + bv, acc[1][j] + bv, acc[2][j] + bv, acc[3][j] + bv };
            const int m = m0 + ty * 4;
            const int bb = m >> 12, s = m & (SEQ - 1);
            const int h = n >> 6, d = n & (DK - 1);
            *(float4*)(C + ((size_t)((bb * NHEADS + h) * DK + d)) * SEQ + s) = o;
        }
    }
}

// ============================================================================
// Flash attention, fp16 MFMA (16x16x32), fp32 accum.
//   S^T = K·Q^T  -> softmax state per-lane (query = lane&15)
//   O^T = V^T·P^T -> V^T A-frags are row-major reads of dim-major V tile;
//                    P B-frags are row-major reads of the per-wave P buffer.
// Block = 256 thr (4 waves), 128 queries/block (32/wave), 64-key iterations.
// ============================================================================
__global__ __launch_bounds__(256)
void attn_mfma(const float* __restrict__ Q, const float* __restrict__ Kg,
               const float* __restrict__ Vt, float* __restrict__ O) {
    // row stride 72 f16 (144 B): b128 rows land 4*(row+quad) banks apart ->
    // exactly 8 dwords/bank per wave access = the 1KB/instr floor.
    __shared__ __align__(16) _Float16 sQ[128 * 72];   // reused as P after Q-frag load
    __shared__ __align__(16) _Float16 sK[64 * 72];
    __shared__ __align__(16) _Float16 sV[64 * 72];    // dim-major (V^T)

    const int t    = threadIdx.x;
    const int lane = t & 63;
    const int wave = t >> 6;
    const int col  = lane & 15;
    const int quad = lane >> 4;

    const int q0 = blockIdx.x * 128;
    const int h  = blockIdx.y;
    const int b  = blockIdx.z;

    const size_t qkBase = (size_t)b * SEQ * D_MODEL + (size_t)h * DK;   // [s][512] rows
    const size_t vBase  = ((size_t)(b * NHEADS + h)) * DK * SEQ;        // [d][4096] rows

    // ---- stage Q tile (128 x 64) as f16 ----
    {
        const int r = t >> 4, c4 = (t & 15) * 4;
        #pragma unroll
        for (int u = 0; u < 8; ++u) {
            float4 v = *(const float4*)(Q + qkBase + (size_t)(q0 + u * 16 + r) * D_MODEL + c4);
            pack4_store(&sQ[(u * 16 + r) * 72 + c4], v);
        }
    }
    __syncthreads();

    // ---- Q B-fragments (hoisted; wave owns queries wave*32 .. +31) ----
    half8 qf[2][2];
    #pragma unroll
    for (int nt = 0; nt < 2; ++nt)
        #pragma unroll
        for (int kc = 0; kc < 2; ++kc)
            qf[nt][kc] = *(const half8*)&sQ[(wave * 32 + nt * 16 + col) * 72 + kc * 32 + quad * 8];
    __syncthreads();   // sQ now dead -> becomes per-wave P staging

    _Float16* Ps = sQ + wave * 32 * 72;   // 32 rows x 72, private to this wave

    float m_r[2] = { -INFINITY, -INFINITY };
    float l_r[2] = { 0.0f, 0.0f };
    f32x4 of[4][2] = {};   // [dt][qt] : O^T frags, dim rows / query cols

    for (int k0 = 0; k0 < SEQ; k0 += 64) {
        __syncthreads();   // prior iteration done with sK/sV
        {
            const int r = t >> 4, c4 = (t & 15) * 4;
            #pragma unroll
            for (int u = 0; u < 4; ++u) {
                float4 kv = *(const float4*)(Kg + qkBase + (size_t)(k0 + u * 16 + r) * D_MODEL + c4);
                float4 vv = *(const float4*)(Vt + vBase + (size_t)(u * 16 + r) * SEQ + k0 + c4);
                pack4_store(&sK[(u * 16 + r) * 72 + c4], kv);
                pack4_store(&sV[(u * 16 + r) * 72 + c4], vv);
            }
        }
        __syncthreads();

        // ---- S^T = K · Q^T : 16 MFMA ----
        f32x4 sf[4][2] = {};   // [kt][nt]: key rows, query cols
        #pragma unroll
        for (int kc = 0; kc < 2; ++kc) {
            #pragma unroll
            for (int kt = 0; kt < 4; ++kt) {
                half8 kf = *(const half8*)&sK[(kt * 16 + col) * 72 + kc * 32 + quad * 8];
                #pragma unroll
                for (int nt = 0; nt < 2; ++nt)
                    sf[kt][nt] = __builtin_amdgcn_mfma_f32_16x16x32_f16(kf, qf[nt][kc], sf[kt][nt], 0, 0, 0);
            }
        }

        // ---- online softmax (log2 domain), P -> per-wave LDS in B-frag rows ----
        #pragma unroll
        for (int nt = 0; nt < 2; ++nt) {
            float mx = sf[0][nt][0];
            #pragma unroll
            for (int kt = 0; kt < 4; ++kt)
                #pragma unroll
                for (int r = 0; r < 4; ++r)
                    mx = fmaxf(mx, sf[kt][nt][r]);
            mx = fmaxf(mx, __shfl_xor(mx, 16));
            mx = fmaxf(mx, __shfl_xor(mx, 32));
            const float mnew = fmaxf(m_r[nt], mx);
            const float al   = exp2f(m_r[nt] - mnew);   // 0 on first tile
            m_r[nt] = mnew;

            float rs = 0.0f;
            #pragma unroll
            for (int kt = 0; kt < 4; ++kt) {
                const float p0 = exp2f(sf[kt][nt][0] - mnew);
                const float p1 = exp2f(sf[kt][nt][1] - mnew);
                const float p2 = exp2f(sf[kt][nt][2] - mnew);
                const float p3 = exp2f(sf[kt][nt][3] - mnew);
                rs += (p0 + p1) + (p2 + p3);
                union { pkhalf2 hh[2]; uint2 u; } z;
                z.hh[0] = __builtin_amdgcn_cvt_pkrtz(p0, p1);
                z.hh[1] = __builtin_amdgcn_cvt_pkrtz(p2, p3);
                *(uint2*)&Ps[(nt * 16 + col) * 72 + kt * 16 + quad * 4] = z.u;
            }
            rs += __shfl_xor(rs, 16);
            rs += __shfl_xor(rs, 32);
            l_r[nt] = l_r[nt] * al + rs;

            #pragma unroll
            for (int dt = 0; dt < 4; ++dt)
                #pragma unroll
                for (int r = 0; r < 4; ++r)
                    of[dt][nt][r] *= al;
        }
        // intra-wave Ps write->read: compiler-inserted lgkmcnt, no barrier needed

        // ---- O^T += V^T · P^T : 16 MFMA ----
        #pragma unroll
        for (int kc = 0; kc < 2; ++kc) {
            half8 pf0 = *(const half8*)&Ps[(0 * 16 + col) * 72 + kc * 32 + quad * 8];
            half8 pf1 = *(const half8*)&Ps[(1 * 16 + col) * 72 + kc * 32 + quad * 8];
            #pragma unroll
            for (int dt = 0; dt < 4; ++dt) {
                half8 vf = *(const half8*)&sV[(dt * 16 + col) * 72 + kc * 32 + quad * 8];
                of[dt][0] = __builtin_amdgcn_mfma_f32_16x16x32_f16(vf, pf0, of[dt][0], 0, 0, 0);
                of[dt][1] = __builtin_amdgcn_mfma_f32_16x16x32_f16(vf, pf1, of[dt][1], 0, 0, 0);
            }
        }
    }

    // ---- normalize, store (float4 along dim: regs are 4 consecutive dims) ----
    #pragma unroll
    for (int qt = 0; qt < 2; ++qt) {
        const float inv = 1.0f / l_r[qt];
        const size_t row = qkBase + (size_t)(q0 + wave * 32 + qt * 16 + col) * D_MODEL;
        #pragma unroll
        for (int dt = 0; dt < 4; ++dt) {
            float4 o = { of[dt][qt][0] * inv, of[dt][qt][1] * inv,
                         of[dt][qt][2] * inv, of[dt][qt][3] * inv };
            *(float4*)(O + row + dt * 16 + quad * 4) = o;
        }
    }
}

// ============================================================================
extern "C" void kernel_launch(void* const* d_in, const int* in_sizes, int n_in,
                              void* d_out, int out_size, void* d_ws, size_t ws_size,
                              hipStream_t stream) {
    const float* query = (const float*)d_in[0];
    const float* key   = (const float*)d_in[1];
    const float* value = (const float*)d_in[2];
    const float* w_q   = (const float*)d_in[3];
    const float* b_q   = (const float*)d_in[4];
    const float* w_k   = (const float*)d_in[5];
    const float* b_k   = (const float*)d_in[6];
    const float* w_v   = (const float*)d_in[7];
    const float* b_v   = (const float*)d_in[8];
    const float* w_o   = (const float*)d_in[9];
    const float* b_o   = (const float*)d_in[10];
    float* out = (float*)d_out;

    const int M = BATCH * SEQ;                  // 8192
    const size_t plane = (size_t)M * D_MODEL;   // 16 MB each

    float* Qb  = (float*)d_ws;
    float* Kb  = Qb + plane;
    float* Vtb = Kb + plane;   // holds V^T in [b][h][d][s]
    float* Ab  = Vtb + plane;

    dim3 blk(256);
    dim3 ggrid(D_MODEL / GBN, M / GBM);

    hipLaunchKernelGGL(gemm_nt_bias, ggrid, blk, 0, stream,
                       query, w_q, b_q, Qb, M, D_MODEL, D_MODEL, ATTN_SCALE, 0);
    hipLaunchKernelGGL(gemm_nt_bias, ggrid, blk, 0, stream,
                       key,   w_k, b_k, Kb, M, D_MODEL, D_MODEL, 1.0f, 0);
    hipLaunchKernelGGL(gemm_nt_bias, ggrid, blk, 0, stream,
                       value, w_v, b_v, Vtb, M, D_MODEL, D_MODEL, 1.0f, 1);

    dim3 agrid(SEQ / 128, NHEADS, BATCH);       // (32, 8, 2)
    hipLaunchKernelGGL(attn_mfma, agrid, blk, 0, stream, Qb, Kb, Vtb, Ab);

    hipLaunchKernelGGL(gemm_nt_bias, ggrid, blk, 0, stream,
                       Ab, w_o, b_o, out, M, D_MODEL, D_MODEL, 1.0f, 0);
}

// Round 4
// 422.713 us; speedup vs baseline: 4.6344x; 1.5944x over previous
//
#include <hip/hip_runtime.h>
#include <math.h>

#define D_MODEL 512
#define NHEADS 8
#define DK 64
#define BATCH 2
#define SEQ 4096
// log2(e)/8 folded into Q projection: scores in log2 domain, softmax uses exp2.
#define ATTN_SCALE 0.18033688011112043f
#define SPLIT_SCALE 2048.0f     // 2^11: lo plane pre-scaled to stay in fp16 normal range
#define INV_SPLIT  (1.0f/2048.0f)

typedef _Float16 half8 __attribute__((ext_vector_type(8)));
typedef float f32x4 __attribute__((ext_vector_type(4)));

union Pk8 { _Float16 h[8]; uint4 u; };
union Pk4 { _Float16 h[4]; uint2 u; };

#define MFMA16(a, b, c) __builtin_amdgcn_mfma_f32_16x16x32_f16((a), (b), (c), 0, 0, 0)

// ============================================================================
// split_fp32: x -> hi = fp16(x), lo = fp16((x - hi) * 2048).  n multiple of 1024.
// ============================================================================
__global__ __launch_bounds__(256)
void split_fp32(const float* __restrict__ src, _Float16* __restrict__ hi,
                _Float16* __restrict__ lo, int n) {
    const int i = (blockIdx.x * 256 + threadIdx.x) * 4;
    if (i >= n) return;
    float4 v = *(const float4*)(src + i);
    Pk4 h, l;
    h.h[0] = (_Float16)v.x; h.h[1] = (_Float16)v.y;
    h.h[2] = (_Float16)v.z; h.h[3] = (_Float16)v.w;
    l.h[0] = (_Float16)((v.x - (float)h.h[0]) * SPLIT_SCALE);
    l.h[1] = (_Float16)((v.y - (float)h.h[1]) * SPLIT_SCALE);
    l.h[2] = (_Float16)((v.z - (float)h.h[2]) * SPLIT_SCALE);
    l.h[3] = (_Float16)((v.w - (float)h.h[3]) * SPLIT_SCALE);
    *(uint2*)(hi + i) = h.u;
    *(uint2*)(lo + i) = l.u;
}

// ============================================================================
// QKV projection GEMM, MFMA fp16. A fp32 (converted hi-only at staging),
// W pre-split (hi + lo*2048). out = alpha*(A@W^T + b) as fp16.
// z=0: Q -> Qf [b*s][512], alpha=ATTN_SCALE.  z=1: K -> Kf.  z=2: V -> Vtf
// transposed per-head [b*8+h][d][s].
// Block 128x128, BK=64, 4 waves (2x2), wave tile 64x64 (16 MFMA tiles).
// ============================================================================
__global__ __launch_bounds__(256)
void gemm_qkv(const float* __restrict__ Aq, const float* __restrict__ Ak,
              const float* __restrict__ Av,
              const _Float16* __restrict__ Whq, const _Float16* __restrict__ Wlq,
              const _Float16* __restrict__ Whk, const _Float16* __restrict__ Wlk,
              const _Float16* __restrict__ Whv, const _Float16* __restrict__ Wlv,
              const float* __restrict__ bq, const float* __restrict__ bk,
              const float* __restrict__ bv,
              _Float16* __restrict__ Qf, _Float16* __restrict__ Kf,
              _Float16* __restrict__ Vtf) {
    const int z = blockIdx.z;
    const float*     A    = z == 0 ? Aq  : (z == 1 ? Ak  : Av);
    const _Float16*  Wh   = z == 0 ? Whq : (z == 1 ? Whk : Whv);
    const _Float16*  Wl   = z == 0 ? Wlq : (z == 1 ? Wlk : Wlv);
    const float*     bias = z == 0 ? bq  : (z == 1 ? bk  : bv);

    // padded 72-half rows: b128 frag reads land 8 dwords/bank (minimum)
    __shared__ __align__(16) _Float16 sA [128 * 72];
    __shared__ __align__(16) _Float16 sWh[128 * 72];
    __shared__ __align__(16) _Float16 sWl[128 * 72];

    const int t    = threadIdx.x;
    const int lane = t & 63, wave = t >> 6;
    const int col  = lane & 15, quad = lane >> 4;
    const int wm   = (wave & 1) * 64, wn = (wave >> 1) * 64;
    const int m0   = blockIdx.y * 128, n0 = blockIdx.x * 128;

    f32x4 acc_h[4][4] = {};   // A_h * W_h
    f32x4 acc_x[4][4] = {};   // A_h * W_l'   (scaled by 2048)

    for (int k0 = 0; k0 < 512; k0 += 64) {
        // ---- global loads (overlap previous chunk's MFMA) ----
        float4 a0[4], a1[4];
        uint4  wh4[4], wl4[4];
        #pragma unroll
        for (int i2 = 0; i2 < 4; ++i2) {
            const int slot = t + i2 * 256;          // 128 rows x 8 segs of 8 elems
            const int r = slot >> 3, sl = slot & 7;
            const float* ap = A + (size_t)(m0 + r) * 512 + k0 + sl * 8;
            a0[i2] = *(const float4*)ap;
            a1[i2] = *(const float4*)(ap + 4);
            wh4[i2] = *(const uint4*)(Wh + (size_t)(n0 + r) * 512 + k0 + sl * 8);
            wl4[i2] = *(const uint4*)(Wl + (size_t)(n0 + r) * 512 + k0 + sl * 8);
        }
        __syncthreads();   // prior chunk's frag reads complete
        #pragma unroll
        for (int i2 = 0; i2 < 4; ++i2) {
            const int slot = t + i2 * 256;
            const int r = slot >> 3, sl = slot & 7;
            Pk8 pk;
            pk.h[0] = (_Float16)a0[i2].x; pk.h[1] = (_Float16)a0[i2].y;
            pk.h[2] = (_Float16)a0[i2].z; pk.h[3] = (_Float16)a0[i2].w;
            pk.h[4] = (_Float16)a1[i2].x; pk.h[5] = (_Float16)a1[i2].y;
            pk.h[6] = (_Float16)a1[i2].z; pk.h[7] = (_Float16)a1[i2].w;
            *(uint4*)&sA [r * 72 + sl * 8] = pk.u;
            *(uint4*)&sWh[r * 72 + sl * 8] = wh4[i2];
            *(uint4*)&sWl[r * 72 + sl * 8] = wl4[i2];
        }
        __syncthreads();

        #pragma unroll
        for (int kc = 0; kc < 2; ++kc) {
            half8 af[4], whf[4], wlf[4];
            #pragma unroll
            for (int mt = 0; mt < 4; ++mt)
                af[mt] = *(const half8*)&sA[(wm + mt * 16 + col) * 72 + kc * 32 + quad * 8];
            #pragma unroll
            for (int nt = 0; nt < 4; ++nt) {
                whf[nt] = *(const half8*)&sWh[(wn + nt * 16 + col) * 72 + kc * 32 + quad * 8];
                wlf[nt] = *(const half8*)&sWl[(wn + nt * 16 + col) * 72 + kc * 32 + quad * 8];
            }
            #pragma unroll
            for (int mt = 0; mt < 4; ++mt)
                #pragma unroll
                for (int nt = 0; nt < 4; ++nt) {
                    acc_h[mt][nt] = MFMA16(af[mt], whf[nt], acc_h[mt][nt]);
                    acc_x[mt][nt] = MFMA16(af[mt], wlf[nt], acc_x[mt][nt]);
                }
        }
    }

    // ---- epilogue: c = alpha*(acc_h + acc_x/2048 + bias) ----
    float bv4[4];
    #pragma unroll
    for (int nt = 0; nt < 4; ++nt) bv4[nt] = bias[n0 + wn + nt * 16 + col];

    if (z < 2) {
        _Float16* Out = z == 0 ? Qf : Kf;
        const float alpha = z == 0 ? ATTN_SCALE : 1.0f;
        #pragma unroll
        for (int mt = 0; mt < 4; ++mt) {
            const int m = m0 + wm + mt * 16 + quad * 4;
            #pragma unroll
            for (int nt = 0; nt < 4; ++nt) {
                const int n = n0 + wn + nt * 16 + col;
                #pragma unroll
                for (int r = 0; r < 4; ++r) {
                    const float c = (acc_h[mt][nt][r] + acc_x[mt][nt][r] * INV_SPLIT + bv4[nt]) * alpha;
                    Out[(size_t)(m + r) * 512 + n] = (_Float16)c;
                }
            }
        }
    } else {
        #pragma unroll
        for (int mt = 0; mt < 4; ++mt) {
            const int m = m0 + wm + mt * 16 + quad * 4;
            const int b = m >> 12, s = m & (SEQ - 1);
            #pragma unroll
            for (int nt = 0; nt < 4; ++nt) {
                const int n = n0 + wn + nt * 16 + col;
                const int hh = n >> 6, d = n & (DK - 1);
                Pk4 p;
                #pragma unroll
                for (int r = 0; r < 4; ++r)
                    p.h[r] = (_Float16)(acc_h[mt][nt][r] + acc_x[mt][nt][r] * INV_SPLIT + bv4[nt]);
                *(uint2*)&Vtf[((size_t)((b * NHEADS + hh) * DK + d)) * SEQ + s] = p.u;
            }
        }
    }
}

// ============================================================================
// Flash attention, fp16 in / fp16 hi+lo out.
//   S^T = K·Q^T (softmax state per-lane), O^T = V^T·P^T.
// Block 256 thr, 128 queries (32/wave), 64-key iterations.
// ============================================================================
__global__ __launch_bounds__(256)
void attn_mfma(const _Float16* __restrict__ Qf, const _Float16* __restrict__ Kf,
               const _Float16* __restrict__ Vtf,
               _Float16* __restrict__ Oh, _Float16* __restrict__ Ol) {
    __shared__ __align__(16) _Float16 sQ[128 * 72];   // becomes per-wave P after Q-frag load
    __shared__ __align__(16) _Float16 sK[64 * 72];
    __shared__ __align__(16) _Float16 sV[64 * 72];    // dim-major (V^T)

    const int t    = threadIdx.x;
    const int lane = t & 63;
    const int wave = t >> 6;
    const int col  = lane & 15;
    const int quad = lane >> 4;

    const int q0 = blockIdx.x * 128;
    const int h  = blockIdx.y;
    const int b  = blockIdx.z;

    const size_t rowBase = (size_t)b * SEQ;                       // row index base
    const size_t vBase   = ((size_t)(b * NHEADS + h)) * DK * SEQ; // halves

    // ---- stage Q tile (128 x 64 halves) ----
    {
        uint4 qv[4];
        #pragma unroll
        for (int i2 = 0; i2 < 4; ++i2) {
            const int slot = t + i2 * 256;   // 128 rows x 8 segs
            const int r = slot >> 3, sl = slot & 7;
            qv[i2] = *(const uint4*)(Qf + (rowBase + q0 + r) * 512 + h * 64 + sl * 8);
        }
        #pragma unroll
        for (int i2 = 0; i2 < 4; ++i2) {
            const int slot = t + i2 * 256;
            const int r = slot >> 3, sl = slot & 7;
            *(uint4*)&sQ[r * 72 + sl * 8] = qv[i2];
        }
    }
    __syncthreads();

    half8 qf[2][2];
    #pragma unroll
    for (int nt = 0; nt < 2; ++nt)
        #pragma unroll
        for (int kc = 0; kc < 2; ++kc)
            qf[nt][kc] = *(const half8*)&sQ[(wave * 32 + nt * 16 + col) * 72 + kc * 32 + quad * 8];
    __syncthreads();   // sQ dead -> per-wave P staging

    _Float16* Ps = sQ + wave * 32 * 72;

    float m_r[2] = { -INFINITY, -INFINITY };
    float l_r[2] = { 0.0f, 0.0f };
    f32x4 of[4][2] = {};

    for (int k0 = 0; k0 < SEQ; k0 += 64) {
        // ---- stage K,V tiles (fp16 direct) ----
        uint4 kv[2], vv[2];
        #pragma unroll
        for (int i2 = 0; i2 < 2; ++i2) {
            const int slot = t + i2 * 256;   // 64 rows x 8 segs
            const int r = slot >> 3, sl = slot & 7;
            kv[i2] = *(const uint4*)(Kf + (rowBase + k0 + r) * 512 + h * 64 + sl * 8);
            vv[i2] = *(const uint4*)(Vtf + vBase + (size_t)r * SEQ + k0 + sl * 8);
        }
        __syncthreads();   // prior iteration done with sK/sV/Ps
        #pragma unroll
        for (int i2 = 0; i2 < 2; ++i2) {
            const int slot = t + i2 * 256;
            const int r = slot >> 3, sl = slot & 7;
            *(uint4*)&sK[r * 72 + sl * 8] = kv[i2];
            *(uint4*)&sV[r * 72 + sl * 8] = vv[i2];
        }
        __syncthreads();

        // ---- S^T = K · Q^T ----
        f32x4 sf[4][2] = {};
        #pragma unroll
        for (int kc = 0; kc < 2; ++kc)
            #pragma unroll
            for (int kt = 0; kt < 4; ++kt) {
                half8 kf = *(const half8*)&sK[(kt * 16 + col) * 72 + kc * 32 + quad * 8];
                #pragma unroll
                for (int nt = 0; nt < 2; ++nt)
                    sf[kt][nt] = MFMA16(kf, qf[nt][kc], sf[kt][nt]);
            }

        // ---- online softmax (log2 domain) ----
        #pragma unroll
        for (int nt = 0; nt < 2; ++nt) {
            float mx = sf[0][nt][0];
            #pragma unroll
            for (int kt = 0; kt < 4; ++kt)
                #pragma unroll
                for (int r = 0; r < 4; ++r)
                    mx = fmaxf(mx, sf[kt][nt][r]);
            mx = fmaxf(mx, __shfl_xor(mx, 16));
            mx = fmaxf(mx, __shfl_xor(mx, 32));
            const float mnew = fmaxf(m_r[nt], mx);
            const float al   = exp2f(m_r[nt] - mnew);
            m_r[nt] = mnew;

            float rs = 0.0f;
            #pragma unroll
            for (int kt = 0; kt < 4; ++kt) {
                const float p0 = exp2f(sf[kt][nt][0] - mnew);
                const float p1 = exp2f(sf[kt][nt][1] - mnew);
                const float p2 = exp2f(sf[kt][nt][2] - mnew);
                const float p3 = exp2f(sf[kt][nt][3] - mnew);
                rs += (p0 + p1) + (p2 + p3);
                Pk4 z;
                z.h[0] = (_Float16)p0; z.h[1] = (_Float16)p1;
                z.h[2] = (_Float16)p2; z.h[3] = (_Float16)p3;
                *(uint2*)&Ps[(nt * 16 + col) * 72 + kt * 16 + quad * 4] = z.u;
            }
            rs += __shfl_xor(rs, 16);
            rs += __shfl_xor(rs, 32);
            l_r[nt] = l_r[nt] * al + rs;

            #pragma unroll
            for (int dt = 0; dt < 4; ++dt)
                #pragma unroll
                for (int r = 0; r < 4; ++r)
                    of[dt][nt][r] *= al;
        }

        // ---- O^T += V^T · P^T ----
        #pragma unroll
        for (int kc = 0; kc < 2; ++kc) {
            half8 pf0 = *(const half8*)&Ps[(0 * 16 + col) * 72 + kc * 32 + quad * 8];
            half8 pf1 = *(const half8*)&Ps[(1 * 16 + col) * 72 + kc * 32 + quad * 8];
            #pragma unroll
            for (int dt = 0; dt < 4; ++dt) {
                half8 vf = *(const half8*)&sV[(dt * 16 + col) * 72 + kc * 32 + quad * 8];
                of[dt][0] = MFMA16(vf, pf0, of[dt][0]);
                of[dt][1] = MFMA16(vf, pf1, of[dt][1]);
            }
        }
    }

    // ---- normalize, store hi + lo' planes (exact split for out-proj) ----
    #pragma unroll
    for (int qt = 0; qt < 2; ++qt) {
        const float inv = 1.0f / l_r[qt];
        const size_t base = (rowBase + q0 + wave * 32 + qt * 16 + col) * 512 + h * 64;
        #pragma unroll
        for (int dt = 0; dt < 4; ++dt) {
            float v[4];
            #pragma unroll
            for (int r = 0; r < 4; ++r) v[r] = of[dt][qt][r] * inv;
            Pk4 hh, ll;
            #pragma unroll
            for (int r = 0; r < 4; ++r) {
                hh.h[r] = (_Float16)v[r];
                ll.h[r] = (_Float16)((v[r] - (float)hh.h[r]) * SPLIT_SCALE);
            }
            *(uint2*)(Oh + base + dt * 16 + quad * 4) = hh.u;
            *(uint2*)(Ol + base + dt * 16 + quad * 4) = ll.u;
        }
    }
}

// ============================================================================
// Output projection: full split-fp16 (3 MFMA/tile), fp32 out + bias.
// A = attention O (pre-split hi/lo planes). Same 128x128/BK=64 geometry.
// ============================================================================
__global__ __launch_bounds__(256)
void gemm_out(const _Float16* __restrict__ Ah, const _Float16* __restrict__ Al,
              const _Float16* __restrict__ Wh, const _Float16* __restrict__ Wl,
              const float* __restrict__ bias, float* __restrict__ C) {
    __shared__ __align__(16) _Float16 sAh[128 * 72];
    __shared__ __align__(16) _Float16 sAl[128 * 72];
    __shared__ __align__(16) _Float16 sWh[128 * 72];
    __shared__ __align__(16) _Float16 sWl[128 * 72];

    const int t    = threadIdx.x;
    const int lane = t & 63, wave = t >> 6;
    const int col  = lane & 15, quad = lane >> 4;
    const int wm   = (wave & 1) * 64, wn = (wave >> 1) * 64;
    const int m0   = blockIdx.y * 128, n0 = blockIdx.x * 128;

    f32x4 acc_h[4][4] = {};   // Ah*Wh
    f32x4 acc_x[4][4] = {};   // Ah*Wl' + Al'*Wh  (scaled 2048)

    for (int k0 = 0; k0 < 512; k0 += 64) {
        uint4 ah4[4], al4[4], wh4[4], wl4[4];
        #pragma unroll
        for (int i2 = 0; i2 < 4; ++i2) {
            const int slot = t + i2 * 256;
            const int r = slot >> 3, sl = slot & 7;
            ah4[i2] = *(const uint4*)(Ah + (size_t)(m0 + r) * 512 + k0 + sl * 8);
            al4[i2] = *(const uint4*)(Al + (size_t)(m0 + r) * 512 + k0 + sl * 8);
            wh4[i2] = *(const uint4*)(Wh + (size_t)(n0 + r) * 512 + k0 + sl * 8);
            wl4[i2] = *(const uint4*)(Wl + (size_t)(n0 + r) * 512 + k0 + sl * 8);
        }
        __syncthreads();
        #pragma unroll
        for (int i2 = 0; i2 < 4; ++i2) {
            const int slot = t + i2 * 256;
            const int r = slot >> 3, sl = slot & 7;
            *(uint4*)&sAh[r * 72 + sl * 8] = ah4[i2];
            *(uint4*)&sAl[r * 72 + sl * 8] = al4[i2];
            *(uint4*)&sWh[r * 72 + sl * 8] = wh4[i2];
            *(uint4*)&sWl[r * 72 + sl * 8] = wl4[i2];
        }
        __syncthreads();

        #pragma unroll
        for (int kc = 0; kc < 2; ++kc) {
            half8 ahf[4], alf[4], whf[4], wlf[4];
            #pragma unroll
            for (int mt = 0; mt < 4; ++mt) {
                ahf[mt] = *(const half8*)&sAh[(wm + mt * 16 + col) * 72 + kc * 32 + quad * 8];
                alf[mt] = *(const half8*)&sAl[(wm + mt * 16 + col) * 72 + kc * 32 + quad * 8];
            }
            #pragma unroll
            for (int nt = 0; nt < 4; ++nt) {
                whf[nt] = *(const half8*)&sWh[(wn + nt * 16 + col) * 72 + kc * 32 + quad * 8];
                wlf[nt] = *(const half8*)&sWl[(wn + nt * 16 + col) * 72 + kc * 32 + quad * 8];
            }
            #pragma unroll
            for (int mt = 0; mt < 4; ++mt)
                #pragma unroll
                for (int nt = 0; nt < 4; ++nt) {
                    acc_h[mt][nt] = MFMA16(ahf[mt], whf[nt], acc_h[mt][nt]);
                    acc_x[mt][nt] = MFMA16(ahf[mt], wlf[nt], acc_x[mt][nt]);
                    acc_x[mt][nt] = MFMA16(alf[mt], whf[nt], acc_x[mt][nt]);
                }
        }
    }

    float bv4[4];
    #pragma unroll
    for (int nt = 0; nt < 4; ++nt) bv4[nt] = bias[n0 + wn + nt * 16 + col];

    #pragma unroll
    for (int mt = 0; mt < 4; ++mt) {
        const int m = m0 + wm + mt * 16 + quad * 4;
        #pragma unroll
        for (int nt = 0; nt < 4; ++nt) {
            const int n = n0 + wn + nt * 16 + col;
            #pragma unroll
            for (int r = 0; r < 4; ++r)
                C[(size_t)(m + r) * 512 + n] =
                    acc_h[mt][nt][r] + acc_x[mt][nt][r] * INV_SPLIT + bv4[nt];
        }
    }
}

// ============================================================================
extern "C" void kernel_launch(void* const* d_in, const int* in_sizes, int n_in,
                              void* d_out, int out_size, void* d_ws, size_t ws_size,
                              hipStream_t stream) {
    const float* query = (const float*)d_in[0];
    const float* key   = (const float*)d_in[1];
    const float* value = (const float*)d_in[2];
    const float* w_q   = (const float*)d_in[3];
    const float* b_q   = (const float*)d_in[4];
    const float* w_k   = (const float*)d_in[5];
    const float* b_k   = (const float*)d_in[6];
    const float* w_v   = (const float*)d_in[7];
    const float* b_v   = (const float*)d_in[8];
    const float* w_o   = (const float*)d_in[9];
    const float* b_o   = (const float*)d_in[10];
    float* out = (float*)d_out;

    const int WN = D_MODEL * D_MODEL;          // 262144
    _Float16* base = (_Float16*)d_ws;
    _Float16* whq = base;            _Float16* wlq = whq + WN;
    _Float16* whk = wlq + WN;        _Float16* wlk = whk + WN;
    _Float16* whv = wlk + WN;        _Float16* wlv = whv + WN;
    _Float16* who = wlv + WN;        _Float16* wlo = who + WN;
    const size_t plane = (size_t)BATCH * SEQ * D_MODEL;   // 4.2M halves
    _Float16* Qf  = wlo + WN;
    _Float16* Kf  = Qf + plane;
    _Float16* Vtf = Kf + plane;
    _Float16* Oh  = Vtf + plane;
    _Float16* Ol  = Oh + plane;      // total ws: 4 MB + 5*8 MB = 44 MB

    dim3 blk(256);

    hipLaunchKernelGGL(split_fp32, dim3(WN / 1024), blk, 0, stream, w_q, whq, wlq, WN);
    hipLaunchKernelGGL(split_fp32, dim3(WN / 1024), blk, 0, stream, w_k, whk, wlk, WN);
    hipLaunchKernelGGL(split_fp32, dim3(WN / 1024), blk, 0, stream, w_v, whv, wlv, WN);
    hipLaunchKernelGGL(split_fp32, dim3(WN / 1024), blk, 0, stream, w_o, who, wlo, WN);

    hipLaunchKernelGGL(gemm_qkv, dim3(D_MODEL / 128, BATCH * SEQ / 128, 3), blk, 0, stream,
                       query, key, value,
                       whq, wlq, whk, wlk, whv, wlv,
                       b_q, b_k, b_v, Qf, Kf, Vtf);

    hipLaunchKernelGGL(attn_mfma, dim3(SEQ / 128, NHEADS, BATCH), blk, 0, stream,
                       Qf, Kf, Vtf, Oh, Ol);

    hipLaunchKernelGGL(gemm_out, dim3(D_MODEL / 128, BATCH * SEQ / 128), blk, 0, stream,
                       Oh, Ol, who, wlo, b_o, out);
}